// Round 3
// baseline (578.925 us; speedup 1.0000x reference)
//
#include <hip/hip_runtime.h>
#include <math.h>

// ---- problem sizes ----
constexpr int Bz = 32, Vz = 21, Dz = 512, Pz = 64;
constexpr int INz = Dz * Pz;         // 32768
constexpr int OUTz = 720;
constexpr int Ez = 8, Rz = 16, Hz = 256;
constexpr int Mz = Bz * Vz;          // 672
constexpr int Nz = OUTz + Ez * Rz;   // 848  (base 720 cols + 8*16 lora cols)
constexpr int Kz = INz;              // 32768

// ---- GEMM tiling ----
constexpr int BM = 128, BN = 128, BK = 32;
constexpr int SPLIT = 32;            // split-K factor (grid = 7*6*32 = 1344 blocks)
constexpr int KSL = Kz / SPLIT;      // 1024
constexpr int NCH = KSL / BK;        // 32 chunks per block
constexpr int LDA = 40;              // LDS row stride in halves (80 B)

typedef _Float16 f16x8 __attribute__((ext_vector_type(8)));
typedef __fp16  fp16x2 __attribute__((ext_vector_type(2)));
typedef float f32x4 __attribute__((ext_vector_type(4)));

__device__ __forceinline__ unsigned int cvt2(float a, float b) {
    fp16x2 p = __builtin_amdgcn_cvt_pkrtz(a, b);   // v_cvt_pkrtz_f16_f32
    return __builtin_bit_cast(unsigned int, p);
}

// ===================== fused GEMM (+pooling) =====================
// C[672x848] += x[672x32768] * concat(W_base, lora_A)[848x32768]^T (fp16 MFMA, fp32 acc)
// 512 threads = 8 waves in 2x4 grid; wave tile 64x32; double-buffered LDS, 1 barrier/iter.
__global__ __launch_bounds__(512, 4)
void gemm_pool_kernel(const float* __restrict__ x, const float* __restrict__ Wb,
                      const float* __restrict__ lA, float* __restrict__ C,
                      float* __restrict__ pooled)
{
    __shared__ _Float16 As[2][BM * LDA];
    __shared__ _Float16 Bs[2][BN * LDA];

    const int nt = blockIdx.x;   // 0..6
    const int mt = blockIdx.y;   // 0..5
    const int s  = blockIdx.z;   // 0..31
    const int t  = threadIdx.x;  // 0..511
    const int r  = t >> 2;       // staged row 0..127
    const int q  = t & 3;        // which 8-float quarter of the 32-wide chunk
    const int kbase = s * KSL + q * 8;

    int gm = mt * BM + r;
    const bool mval = (gm < Mz);
    if (!mval) gm = Mz - 1;                      // clamp: dup work, discarded in epilogue
    const float* pa = x + (size_t)gm * Kz + kbase;

    int gn = nt * BN + r;
    if (gn >= Nz) gn = Nz - 1;                   // clamp: garbage cols, discarded
    const float* pb = (gn < OUTz) ? (Wb + (size_t)gn * Kz + kbase)
                                  : (lA + (size_t)(gn - OUTz) * Kz + kbase);

    const int wave = t >> 6, lane = t & 63;
    const int wr = (wave >> 2) * 64;             // wave row base (2 rows of waves)
    const int wc = (wave & 3) * 32;              // wave col base (4 cols of waves)
    const int fl = lane & 15;
    const int ko = (lane >> 4) * 8;              // k offset of this lane's frag

    f32x4 acc[4][2] = {};

    float4 ca0, ca1, cb0, cb1;
    ca0 = *(const float4*)(pa);     ca1 = *(const float4*)(pa + 4);
    cb0 = *(const float4*)(pb);     cb1 = *(const float4*)(pb + 4);

    const bool do_pool = (nt == 0) && mval;
    float* poolrow = pooled + (gm / Vz) * Dz;
    float psum = 0.0f;

    for (int c = 0; c < NCH; ++c) {
        const int buf = c & 1;
        if (do_pool) {   // 8-float run stays within one d-group of 64; pairs of chunks share d
            psum += (ca0.x + ca0.y + ca0.z + ca0.w) + (ca1.x + ca1.y + ca1.z + ca1.w);
            if (c & 1) { atomicAdd(poolrow + ((kbase + c * BK) >> 6), psum); psum = 0.0f; }
        }
        _Float16* wA = &As[buf][r * LDA + q * 8];
        *(uint4*)wA = make_uint4(cvt2(ca0.x, ca0.y), cvt2(ca0.z, ca0.w),
                                 cvt2(ca1.x, ca1.y), cvt2(ca1.z, ca1.w));
        _Float16* wB = &Bs[buf][r * LDA + q * 8];
        *(uint4*)wB = make_uint4(cvt2(cb0.x, cb0.y), cvt2(cb0.z, cb0.w),
                                 cvt2(cb1.x, cb1.y), cvt2(cb1.z, cb1.w));

        if (c + 1 < NCH) {   // register prefetch of next chunk
            const float* qa = pa + (c + 1) * BK;
            const float* qb = pb + (c + 1) * BK;
            ca0 = *(const float4*)(qa);  ca1 = *(const float4*)(qa + 4);
            cb0 = *(const float4*)(qb);  cb1 = *(const float4*)(qb + 4);
        }
        __syncthreads();    // single barrier per iter (write buf -> read buf)

        f16x8 af[4], bfr[2];
        #pragma unroll
        for (int i = 0; i < 4; ++i)
            af[i] = *(const f16x8*)(&As[buf][(wr + i * 16 + fl) * LDA + ko]);
        #pragma unroll
        for (int j = 0; j < 2; ++j)
            bfr[j] = *(const f16x8*)(&Bs[buf][(wc + j * 16 + fl) * LDA + ko]);
        #pragma unroll
        for (int i = 0; i < 4; ++i)
            #pragma unroll
            for (int j = 0; j < 2; ++j)
                acc[i][j] = __builtin_amdgcn_mfma_f32_16x16x32_f16(af[i], bfr[j], acc[i][j], 0, 0, 0);
    }

    // epilogue: split-K accumulate via fp32 atomics.  C/D layout: col=lane&15, row=quad*4+reg
    const int rq = (lane >> 4) * 4;
    #pragma unroll
    for (int i = 0; i < 4; ++i) {
        const int gmr0 = mt * BM + wr + i * 16 + rq;
        #pragma unroll
        for (int j = 0; j < 2; ++j) {
            const int gnc = nt * BN + wc + j * 16 + fl;
            if (gnc < Nz) {
                #pragma unroll
                for (int q2 = 0; q2 < 4; ++q2) {
                    const int gmr = gmr0 + q2;
                    if (gmr < Mz) atomicAdd(&C[(size_t)gmr * Nz + gnc], acc[i][j][q2]);
                }
            }
        }
    }
}

// ===================== router =====================
// coalesced: each wave owns 64 h-rows; lanes split the 512-dot; shuffle-reduce.
__global__ __launch_bounds__(256)
void router_kernel(const float* __restrict__ pooled_raw,
                   const float* __restrict__ Wr1, const float* __restrict__ br1,
                   const float* __restrict__ Wr2, const float* __restrict__ br2,
                   float* __restrict__ probs_out, int* __restrict__ tki, float* __restrict__ tkw)
{
    const int b = blockIdx.x, t = threadIdx.x;
    const int wave = t >> 6, lane = t & 63;
    __shared__ float hbuf[Hz];
    __shared__ float lg[Ez];

    // this lane's 8 pooled values, scaled, held in registers
    const float sc = 1.0f / (float)(Vz * Pz);
    float pv[8];
    const float* prow = pooled_raw + b * Dz + lane * 8;
    #pragma unroll
    for (int u = 0; u < 8; ++u) pv[u] = prow[u] * sc;

    for (int i = 0; i < 64; ++i) {
        const int j = wave * 64 + i;
        const float* wrow = Wr1 + (size_t)j * Dz + lane * 8;   // coalesced across lanes
        float v = 0.0f;
        #pragma unroll
        for (int u = 0; u < 8; ++u) v = fmaf(pv[u], wrow[u], v);
        #pragma unroll
        for (int off = 32; off >= 1; off >>= 1) v += __shfl_down(v, off, 64);
        if (lane == 0) {
            float a = v + br1[j];
            hbuf[j] = 0.5f * a * (1.0f + erff(a * 0.70710678118654752440f));
        }
    }
    __syncthreads();

    if (t < Ez) {
        const float* w = Wr2 + (size_t)t * Hz;
        float a = br2[t];
        for (int j = 0; j < Hz; ++j) a = fmaf(hbuf[j], w[j], a);
        lg[t] = a;
    }
    __syncthreads();

    if (t == 0) {
        float mx = lg[0];
        for (int e = 1; e < Ez; ++e) mx = fmaxf(mx, lg[e]);
        float p[Ez], ssum = 0.0f;
        for (int e = 0; e < Ez; ++e) { p[e] = expf(lg[e] - mx); ssum += p[e]; }
        const float inv = 1.0f / ssum;
        for (int e = 0; e < Ez; ++e) { p[e] *= inv; probs_out[b * Ez + e] = p[e]; }
        int i0 = 0;
        for (int e = 1; e < Ez; ++e) if (p[e] > p[i0]) i0 = e;
        int i1 = (i0 == 0) ? 1 : 0;
        for (int e = 0; e < Ez; ++e) if (e != i0 && p[e] > p[i1]) i1 = e;
        float s2 = p[i0] + p[i1];
        if (s2 < 1e-6f) s2 = 1e-6f;
        tki[b * 2] = i0; tki[b * 2 + 1] = i1;
        tkw[b * 2] = p[i0] / s2; tkw[b * 2 + 1] = p[i1] / s2;
    }
}

// ===================== combine =====================
__global__ __launch_bounds__(256)
void combine_kernel(const float* __restrict__ C, const float* __restrict__ bb,
                    const float* __restrict__ loraB,
                    const int* __restrict__ tki, const float* __restrict__ tkw,
                    float* __restrict__ out)
{
    const int m = blockIdx.x;        // 0..671
    const int t = threadIdx.x;
    const int b = m / Vz;
    const int e0 = tki[b * 2], e1 = tki[b * 2 + 1];
    const float w0 = tkw[b * 2], w1 = tkw[b * 2 + 1];

    __shared__ float lw[2 * Rz];
    if (t < 2 * Rz) {
        const int e = (t < Rz) ? e0 : e1;
        lw[t] = C[(size_t)m * Nz + OUTz + e * Rz + (t & (Rz - 1))];
    }
    __syncthreads();

    for (int o = t; o < OUTz; o += 256) {
        float acc = C[(size_t)m * Nz + o] + bb[o];
        const float* B0 = loraB + ((size_t)e0 * OUTz + o) * Rz;
        const float* B1 = loraB + ((size_t)e1 * OUTz + o) * Rz;
        float d0 = 0.0f, d1 = 0.0f;
        #pragma unroll
        for (int rr = 0; rr < Rz; ++rr) {
            d0 = fmaf(lw[rr], B0[rr], d0);
            d1 = fmaf(lw[Rz + rr], B1[rr], d1);
        }
        out[(size_t)m * OUTz + o] = acc + w0 * d0 + w1 * d1;   // SCALING == 1.0
    }
}

// ===================== launch =====================
extern "C" void kernel_launch(void* const* d_in, const int* in_sizes, int n_in,
                              void* d_out, int out_size, void* d_ws, size_t ws_size,
                              hipStream_t stream)
{
    const float* x   = (const float*)d_in[0];
    const float* Wb  = (const float*)d_in[1];
    const float* bb  = (const float*)d_in[2];
    const float* Wr1 = (const float*)d_in[3];
    const float* br1 = (const float*)d_in[4];
    const float* Wr2 = (const float*)d_in[5];
    const float* br2 = (const float*)d_in[6];
    const float* lA  = (const float*)d_in[7];
    const float* lB  = (const float*)d_in[8];
    float* out = (float*)d_out;

    float* C      = (float*)d_ws;            // 672*848 fp32
    float* pooled = C + (size_t)Mz * Nz;     // 32*512 fp32
    int*   tki    = (int*)(pooled + Bz * Dz);
    float* tkw    = (float*)(tki + 2 * Bz);

    (void)hipMemsetAsync(d_ws, 0, ((size_t)Mz * Nz + Bz * Dz) * sizeof(float), stream);

    gemm_pool_kernel<<<dim3(7, 6, SPLIT), 512, 0, stream>>>(x, Wb, lA, C, pooled);
    router_kernel<<<Bz, 256, 0, stream>>>(pooled, Wr1, br1, Wr2, br2,
                                          out + (size_t)Mz * OUTz, tki, tkw);
    combine_kernel<<<Mz, 256, 0, stream>>>(C, bb, lB, tki, tkw, out);
}